// Round 11
// baseline (70.048 us; speedup 1.0000x reference)
//
#include <hip/hip_runtime.h>

typedef __attribute__((ext_vector_type(8))) short short8;
typedef __attribute__((ext_vector_type(4))) short short4v;
typedef __attribute__((ext_vector_type(4))) float f32x4;

#define VM(n) asm volatile("s_waitcnt vmcnt(" #n ")" ::: "memory")
#define LGKM0 asm volatile("s_waitcnt lgkmcnt(0)" ::: "memory")

namespace {

constexpr int DIN  = 768;
constexpr int HID  = 64;
constexpr int NEXP = 6;
constexpr int CDIM  = 320;
constexpr int NZ    = 64;
constexpr int NTOK  = 20480;

constexpr long long XP_OFF   = 0;
constexpr long long ZP_OFF   = 12582912LL;
constexpr long long LOSS_OFF = 15728640LL;
constexpr long long LG_OFF   = 15728641LL;

__device__ inline unsigned short f2bf(float f) {
  union { float f; unsigned u; } v{f};
  return (unsigned short)((v.u + 0x7FFFu + ((v.u >> 16) & 1u)) >> 16);  // RNE
}
__device__ inline float b2f(unsigned short s) {
  union { unsigned u; float f; } v{(unsigned)s << 16};
  return v.f;
}
__device__ inline void gload16(const void* g, void* l) {
  __builtin_amdgcn_global_load_lds(
      (const __attribute__((address_space(1))) unsigned*)g,
      (__attribute__((address_space(3))) unsigned*)l, 16, 0, 0);
}
// float-offset of token n's output row (also where its bf16 tok staging lives)
__device__ inline int row_base(int n) {
  int bb = n / CDIM, c = n - bb * CDIM;
  return (c < NZ) ? (int)(ZP_OFF + (long long)(bb * NZ + c) * DIN)
                  : (int)(XP_OFF + (long long)(bb * (CDIM - NZ) + (c - NZ)) * DIN);
}

// ---------------- K0: weight prep + gate + tok staging ----------------
// blocks 0-71:  ewb_t[e][h][k] = bf16(expert_w[e][k][h])
// blocks 72-83: fwb = bf16(ffn1_w)
// blocks 84+ :  gate, 16 tokens/block, DMA-pipelined like moe: 12 phases of
//               64 dims; x/xi chunks staged via global_load_lds into dbuf LDS,
//               counted vmcnt + raw barriers; gate math = round-9 verified.
__global__ __launch_bounds__(256) void pre_kernel(
    const float* __restrict__ x, const float* __restrict__ xi,
    const float* __restrict__ wg, const float* __restrict__ ew,
    const float* __restrict__ fw,
    float* __restrict__ out, float4* __restrict__ rec,
    unsigned short* __restrict__ ewb_t, unsigned short* __restrict__ fwb)
{
  int b = blockIdx.x, tid = threadIdx.x;
  // [0,21504): padded wg | [21504,37888): x/xi chunk dbuf (8KB per chunk set)
  __shared__ __align__(16) char sbuf[37888];
  if (b < 72) {
    float (*t_lds)[65] = (float(*)[65])sbuf;
    int e = b / 12, kc = (b % 12) * 64;
    const float* src = ew + (size_t)e * DIN * HID + (size_t)kc * HID;
    #pragma unroll
    for (int it = 0; it < 16; ++it) {
      int f = it * 256 + tid; int ky = f >> 6, h = f & 63;
      t_lds[h][ky] = src[ky * 64 + h];
    }
    __syncthreads();
    unsigned short* dst = ewb_t + (size_t)e * DIN * HID + kc;
    #pragma unroll
    for (int it = 0; it < 16; ++it) {
      int f = it * 256 + tid; int h = f >> 6, ky = f & 63;
      dst[(size_t)h * DIN + ky] = f2bf(t_lds[h][ky]);
    }
    return;
  }
  if (b < 84) {
    int base = (b - 72) * 4096;
    #pragma unroll
    for (int it = 0; it < 16; ++it) {
      int idx = base + it * 256 + tid;
      fwb[idx] = f2bf(fw[idx]);
    }
    return;
  }
  // ---- gate + tok (DMA pipeline) ----
  // padded wg: group g (4 dims) -> 28 floats at g*28; float j = (d&3)*6+e
  float* wgl = (float*)sbuf;
  for (int i = tid; i < NEXP * DIN; i += 256) {
    int d = i / 6, e = i - d * 6;
    wgl[(d >> 2) * 28 + (d & 3) * 6 + e] = wg[i];
  }

  int ls = tid & 15;            // dim-group within token (matches round-9 lane ls)
  int ti = tid >> 4;            // token index within block (0..15)
  int t0 = (b - 84) * 16;
  int n  = t0 + ti;
  int wid = tid >> 6;

  // staging addresses: thread stages 16B of its own (token, dim-group) slot
  const float* xsrc = x  + (size_t)n * DIN + ls * 4;
  const float* isrc = xi + (size_t)n * DIN + ls * 4;
  char* bufb = sbuf + 21504;                 // dbuf base
  int soff = wid * 1024 + (tid & 63) * 16;   // wave-uniform base + lane*16

  unsigned short* tk = (unsigned short*)out + (size_t)row_base(n) * 2;

  float lg[NEXP];
  #pragma unroll
  for (int e = 0; e < NEXP; ++e) lg[e] = 0.f;

  // prologue: chunk 0
  gload16(xsrc, bufb + soff);
  gload16(isrc, bufb + 4096 + soff);
  LGKM0;                // wg staging writes drained before first barrier

  for (int k = 0; k < 12; ++k) {
    char* cur = bufb + (k & 1) * 8192;
    char* nxt = bufb + ((k + 1) & 1) * 8192;
    if (k < 11) {
      gload16(xsrc + (k + 1) * 64, nxt + soff);
      gload16(isrc + (k + 1) * 64, nxt + 4096 + soff);
      VM(2);            // chunk k complete; k+1's 2 loads stay in flight
    } else {
      VM(0);
    }
    __builtin_amdgcn_s_barrier();
    __builtin_amdgcn_sched_barrier(0);
    float4 a = *(const float4*)(cur + ti * 256 + ls * 16);
    float4 q = *(const float4*)(cur + 4096 + ti * 256 + ls * 16);
    float tv0 = a.x + q.x, tv1 = a.y + q.y, tv2 = a.z + q.z, tv3 = a.w + q.w;
    short4v t4;
    t4[0] = (short)f2bf(tv0); t4[1] = (short)f2bf(tv1);
    t4[2] = (short)f2bf(tv2); t4[3] = (short)f2bf(tv3);
    *(short4v*)(tk + ls * 4 + 64 * k) = t4;
    const float4* wq = (const float4*)(wgl + (ls + 16 * k) * 28);
    float4 w0 = wq[0], w1 = wq[1], w2 = wq[2], w3 = wq[3], w4 = wq[4], w5 = wq[5];
    lg[0] += tv0 * w0.x; lg[1] += tv0 * w0.y; lg[2] += tv0 * w0.z;
    lg[3] += tv0 * w0.w; lg[4] += tv0 * w1.x; lg[5] += tv0 * w1.y;
    lg[0] += tv1 * w1.z; lg[1] += tv1 * w1.w; lg[2] += tv1 * w2.x;
    lg[3] += tv1 * w2.y; lg[4] += tv1 * w2.z; lg[5] += tv1 * w2.w;
    lg[0] += tv2 * w3.x; lg[1] += tv2 * w3.y; lg[2] += tv2 * w3.z;
    lg[3] += tv2 * w3.w; lg[4] += tv2 * w4.x; lg[5] += tv2 * w4.y;
    lg[0] += tv3 * w4.z; lg[1] += tv3 * w4.w; lg[2] += tv3 * w5.x;
    lg[3] += tv3 * w5.y; lg[4] += tv3 * w5.z; lg[5] += tv3 * w5.w;
    LGKM0;              // LDS reads done before other waves' next-chunk DMA lands
    __builtin_amdgcn_s_barrier();
  }

  // reduce over the 16 lanes of this token's group (round-9 verified)
  #pragma unroll
  for (int e = 0; e < NEXP; ++e) {
    float v = lg[e];
    v += __shfl_xor(v, 1, 64);
    v += __shfl_xor(v, 2, 64);
    v += __shfl_xor(v, 4, 64);
    v += __shfl_xor(v, 8, 64);
    lg[e] = v;
  }
  // top-2 (computed uniformly by all 16 lanes of the group)
  int e0 = 0; float v0 = lg[0];
  #pragma unroll
  for (int j = 1; j < NEXP; ++j) if (lg[j] > v0) { v0 = lg[j]; e0 = j; }
  int e1 = 0; float v1 = -3.4e38f;
  #pragma unroll
  for (int j = 0; j < NEXP; ++j) if (j != e0 && lg[j] > v1) { v1 = lg[j]; e1 = j; }
  float g0 = 1.f / (1.f + expf(v1 - v0));
  if (ls < NEXP) {
    float myv = lg[0];
    #pragma unroll
    for (int e = 1; e < NEXP; ++e) if (ls == e) myv = lg[e];
    out[LG_OFF + (size_t)n * NEXP + ls] = myv;
  }
  if (ls == 0) rec[n] = make_float4((float)e0, (float)e1, g0, 1.f - g0);
}

// ---------------- K1: GEMM (all experts) + combine + FFN, counted-vmcnt ----
// M=64 tok/block, N=384, BK=32, 24 phases, 512 threads (8 waves 2x4).
// Block 320 computes the load-balance loss.  (round-4 verified, verbatim)
__global__ __launch_bounds__(512) void moe_kernel(
    const unsigned short* __restrict__ ewb_t, const float* __restrict__ eb,
    const unsigned short* __restrict__ fwb, const float* __restrict__ fb,
    const float4* __restrict__ rec, float* __restrict__ out)
{
  __shared__ __align__(16) char smem[74752];
  __shared__ int rb[64];
  __shared__ float simp[8][NEXP], sld[8][NEXP];

  int tid = threadIdx.x, lane = tid & 63, wid = tid >> 6;
  int qw = lane >> 4, l15 = lane & 15;
  int wm = wid >> 2, wn = wid & 3;

  if (blockIdx.x == 320) {   // ---- loss ----
    float imp[NEXP], ld[NEXP];
    #pragma unroll
    for (int e = 0; e < NEXP; ++e) { imp[e] = 0.f; ld[e] = 0.f; }
    for (int n = tid; n < NTOK; n += 512) {
      float4 r = rec[n];
      int e0 = (int)r.x, e1 = (int)r.y;
      #pragma unroll
      for (int e = 0; e < NEXP; ++e) {
        imp[e] += (e == e0 ? r.z : 0.f) + (e == e1 ? r.w : 0.f);
        ld[e]  += (e == e0 ? 1.f : 0.f) + (e == e1 ? 1.f : 0.f);
      }
    }
    #pragma unroll
    for (int e = 0; e < NEXP; ++e) {
      float a = imp[e], bq = ld[e];
      #pragma unroll
      for (int off = 32; off >= 1; off >>= 1) {
        a += __shfl_xor(a, off, 64);
        bq += __shfl_xor(bq, off, 64);
      }
      imp[e] = a; ld[e] = bq;
    }
    if (lane == 0) {
      #pragma unroll
      for (int e = 0; e < NEXP; ++e) { simp[wid][e] = imp[e]; sld[wid][e] = ld[e]; }
    }
    __syncthreads();
    if (tid == 0) {
      float It[NEXP], Lt[NEXP], mi = 0.f, ml = 0.f;
      #pragma unroll
      for (int e = 0; e < NEXP; ++e) {
        It[e] = 0.f; Lt[e] = 0.f;
        #pragma unroll
        for (int w = 0; w < 8; ++w) { It[e] += simp[w][e]; Lt[e] += sld[w][e]; }
        mi += It[e]; ml += Lt[e];
      }
      mi /= NEXP; ml /= NEXP;
      float vi = 0.f, vl = 0.f;
      #pragma unroll
      for (int e = 0; e < NEXP; ++e) {
        vi += (It[e] - mi) * (It[e] - mi);
        vl += (Lt[e] - ml) * (Lt[e] - ml);
      }
      vi /= NEXP; vl /= NEXP;
      out[LOSS_OFF] = vi / (mi * mi + 1e-10f) + vl / (ml * ml + 1e-10f);
    }
    return;
  }

  int t0 = blockIdx.x * 64;
  const unsigned short* tokb = (const unsigned short*)out;

  // per-thread staging sources
  size_t b_src[3]; int b_dst[3];
  #pragma unroll
  for (int it = 0; it < 3; ++it) {
    int F = it * 512 + tid, r = F >> 2, s = F & 3;
    b_src[it] = (size_t)r * DIN + ((s ^ (r & 3) ^ ((r & 4) >> 1)) << 3);
    b_dst[it] = (it * 512 + wid * 64) * 16;
  }
  int ar = tid >> 2, as = tid & 3;
  size_t a_src = (size_t)row_base(t0 + ar) * 2 +
                 ((as ^ (ar & 3) ^ ((ar & 4) >> 1)) << 3);
  int a_dst = (wid * 64) * 16;

  if (tid < 64) rb[tid] = row_base(t0 + tid);

  // prologue: chunk 0
  #pragma unroll
  for (int it = 0; it < 3; ++it)
    gload16(ewb_t + b_src[it], smem + 8192 + b_dst[it]);
  if (tid < 256) gload16(tokb + a_src, smem + a_dst);

  f32x4 acc[2][6];
  #pragma unroll
  for (int m = 0; m < 2; ++m)
    #pragma unroll
    for (int n = 0; n < 6; ++n) acc[m][n] = (f32x4){0.f, 0.f, 0.f, 0.f};

  int aoff[2], boff[6];
  #pragma unroll
  for (int m = 0; m < 2; ++m) {
    int row = wm * 32 + m * 16 + l15;
    aoff[m] = row * 64 + ((qw ^ (row & 3) ^ ((row & 4) >> 1)) << 4);
  }
  #pragma unroll
  for (int n = 0; n < 6; ++n) {
    int row = wn * 96 + n * 16 + l15;
    boff[n] = row * 64 + ((qw ^ (row & 3) ^ ((row & 4) >> 1)) << 4);
  }

  // K-loop: 24 phases, counted vmcnt, 2 raw barriers per phase
  for (int k = 0; k < 24; ++k) {
    const char* cA = smem + (k & 1) * 4096;
    const char* cB = smem + 8192 + (k & 1) * 24576;
    char* nA = (char*)smem + ((k + 1) & 1) * 4096;
    char* nB = (char*)smem + 8192 + ((k + 1) & 1) * 24576;
    if (k < 23) {
      #pragma unroll
      for (int it = 0; it < 3; ++it)
        gload16(ewb_t + b_src[it] + (k + 1) * 32, nB + b_dst[it]);
      if (tid < 256) gload16(tokb + a_src + (k + 1) * 32, nA + a_dst);
      if (wid < 4) VM(4); else VM(3);
    } else {
      VM(0);
    }
    __builtin_amdgcn_s_barrier();
    __builtin_amdgcn_sched_barrier(0);
    short8 af[2], bfv[6];
    #pragma unroll
    for (int m = 0; m < 2; ++m) af[m] = *(const short8*)(cA + aoff[m]);
    #pragma unroll
    for (int n = 0; n < 6; ++n) bfv[n] = *(const short8*)(cB + boff[n]);
    __builtin_amdgcn_s_setprio(1);
    #pragma unroll
    for (int m = 0; m < 2; ++m)
      #pragma unroll
      for (int n = 0; n < 6; ++n)
        acc[m][n] = __builtin_amdgcn_mfma_f32_16x16x32_bf16(af[m], bfv[n], acc[m][n], 0, 0, 0);
    __builtin_amdgcn_s_setprio(0);
    __builtin_amdgcn_sched_barrier(0);
    __builtin_amdgcn_s_barrier();
  }

  // issue fwb chunk 0 into HI buffer (in flight during h/combine)
  #pragma unroll
  for (int it = 0; it < 2; ++it) {
    int F = it * 512 + tid, r = F >> 3, s = F & 7;
    gload16(fwb + (size_t)r * HID + ((s ^ (r & 7)) << 3),
            smem + 58368 + (it * 512 + wid * 64) * 16);
  }

  // h -> LDS bf16 [64][392]
  unsigned short* hl = (unsigned short*)(smem + 8192);
  #pragma unroll
  for (int m = 0; m < 2; ++m)
    #pragma unroll
    for (int n = 0; n < 6; ++n)
      #pragma unroll
      for (int i = 0; i < 4; ++i) {
        int row = wm * 32 + m * 16 + qw * 4 + i;
        int col = wn * 96 + n * 16 + l15;
        hl[row * 392 + col] = f2bf(acc[m][n][i]);
      }
  LGKM0;
  __builtin_amdgcn_s_barrier();

  // gated combine -> y bf16 (swizzled) at smem[0,8192)
  {
    int t = tid >> 3, j0 = (tid & 7) * 8;
    float4 rr = rec[t0 + t];
    int e0 = (int)rr.x, e1 = (int)rr.y;
    float g0 = rr.z, g1 = rr.w;
    short8 h0 = *(const short8*)(hl + t * 392 + e0 * 64 + j0);
    short8 h1 = *(const short8*)(hl + t * 392 + e1 * 64 + j0);
    const float4* ep0 = (const float4*)(eb + e0 * 64 + j0);
    const float4* ep1 = (const float4*)(eb + e1 * 64 + j0);
    float4 b0a = ep0[0], b0b = ep0[1], b1a = ep1[0], b1b = ep1[1];
    float be0[8] = {b0a.x, b0a.y, b0a.z, b0a.w, b0b.x, b0b.y, b0b.z, b0b.w};
    float be1[8] = {b1a.x, b1a.y, b1a.z, b1a.w, b1b.x, b1b.y, b1b.z, b1b.w};
    short8 ov;
    #pragma unroll
    for (int j = 0; j < 8; ++j) {
      float v = g0 * (b2f((unsigned short)h0[j]) + be0[j])
              + g1 * (b2f((unsigned short)h1[j]) + be1[j]);
      ov[j] = (short)f2bf(v);
    }
    *(short8*)(smem + t * 128 + ((((tid & 7)) ^ (t & 7)) << 4)) = ov;
  }
  LGKM0;
  __builtin_amdgcn_s_barrier();

  // FFN: 6 chunks of 128 cols, fwb dbuf HI/LO, counted vmcnt
  for (int c = 0; c < 6; ++c) {
    const char* cF = smem + ((c & 1) ? 8192 : 58368);
    char* nF = (char*)smem + ((c & 1) ? 58368 : 8192);
    if (c < 5) {
      #pragma unroll
      for (int it = 0; it < 2; ++it) {
        int F = it * 512 + tid, r = F >> 3, s = F & 7;
        gload16(fwb + (size_t)((c + 1) * 128 + r) * HID + ((s ^ (r & 7)) << 3),
                nF + (it * 512 + wid * 64) * 16);
      }
      VM(2);
    } else {
      VM(0);
    }
    __builtin_amdgcn_s_barrier();
    __builtin_amdgcn_sched_barrier(0);
    f32x4 a2[2][2];
    #pragma unroll
    for (int m = 0; m < 2; ++m)
      #pragma unroll
      for (int n = 0; n < 2; ++n) a2[m][n] = (f32x4){0.f, 0.f, 0.f, 0.f};
    #pragma unroll
    for (int kk = 0; kk < 2; ++kk) {
      short8 ay[2], bw[2];
      #pragma unroll
      for (int m = 0; m < 2; ++m) {
        int row = wm * 32 + m * 16 + l15;
        ay[m] = *(const short8*)(smem + row * 128 + (((kk * 4 + qw) ^ (row & 7)) << 4));
      }
      #pragma unroll
      for (int n = 0; n < 2; ++n) {
        int rw = wn * 32 + n * 16 + l15;
        bw[n] = *(const short8*)(cF + rw * 128 + (((kk * 4 + qw) ^ (rw & 7)) << 4));
      }
      __builtin_amdgcn_s_setprio(1);
      #pragma unroll
      for (int m = 0; m < 2; ++m)
        #pragma unroll
        for (int n = 0; n < 2; ++n)
          a2[m][n] = __builtin_amdgcn_mfma_f32_16x16x32_bf16(ay[m], bw[n], a2[m][n], 0, 0, 0);
      __builtin_amdgcn_s_setprio(0);
    }
    #pragma unroll
    for (int n = 0; n < 2; ++n) {
      int col = c * 128 + wn * 32 + n * 16 + l15;
      float bias = fb[col];
      #pragma unroll
      for (int m = 0; m < 2; ++m)
        #pragma unroll
        for (int i = 0; i < 4; ++i) {
          int rl = wm * 32 + m * 16 + qw * 4 + i;
          out[(size_t)rb[rl] + col] = a2[m][n][i] + bias;
        }
    }
    __builtin_amdgcn_sched_barrier(0);
    __builtin_amdgcn_s_barrier();
  }
}

}  // namespace

extern "C" void kernel_launch(void* const* d_in, const int* in_sizes, int n_in,
                              void* d_out, int out_size, void* d_ws, size_t ws_size,
                              hipStream_t stream)
{
  const float* x  = (const float*)d_in[0];
  const float* xi = (const float*)d_in[1];
  const float* wg = (const float*)d_in[2];
  const float* ew = (const float*)d_in[3];
  const float* eb = (const float*)d_in[4];
  const float* fw = (const float*)d_in[5];
  const float* fb = (const float*)d_in[6];
  float* out = (float*)d_out;

  char* w = (char*)d_ws;
  float4*         rec   = (float4*)w;                              // 327,680 B
  unsigned short* ewb_t = (unsigned short*)(w + 327680);           // 589,824 B
  unsigned short* fwb   = (unsigned short*)(w + 327680 + 589824);  //  98,304 B

  // gate: 1280 blocks x 16 tokens, DMA-pipelined; +84 weight-prep blocks
  pre_kernel<<<84 + 1280, 256, 0, stream>>>(x, xi, wg, ew, fw, out, rec, ewb_t, fwb);
  moe_kernel<<<321, 512, 0, stream>>>(ewb_t, eb, fwb, fb, rec, out);
}

// Round 12
// 67.336 us; speedup vs baseline: 1.0403x; 1.0403x over previous
//
#include <hip/hip_runtime.h>

typedef __attribute__((ext_vector_type(8))) short short8;
typedef __attribute__((ext_vector_type(4))) short short4v;
typedef __attribute__((ext_vector_type(4))) float f32x4;

#define VM(n) asm volatile("s_waitcnt vmcnt(" #n ")" ::: "memory")
#define LGKM0 asm volatile("s_waitcnt lgkmcnt(0)" ::: "memory")

namespace {

constexpr int DIN  = 768;
constexpr int HID  = 64;
constexpr int NEXP = 6;
constexpr int CDIM  = 320;
constexpr int NZ    = 64;
constexpr int NTOK  = 20480;

constexpr long long XP_OFF   = 0;
constexpr long long ZP_OFF   = 12582912LL;
constexpr long long LOSS_OFF = 15728640LL;
constexpr long long LG_OFF   = 15728641LL;

__device__ inline unsigned short f2bf(float f) {
  union { float f; unsigned u; } v{f};
  return (unsigned short)((v.u + 0x7FFFu + ((v.u >> 16) & 1u)) >> 16);  // RNE
}
__device__ inline float b2f(unsigned short s) {
  union { unsigned u; float f; } v{(unsigned)s << 16};
  return v.f;
}
__device__ inline void gload16(const void* g, void* l) {
  __builtin_amdgcn_global_load_lds(
      (const __attribute__((address_space(1))) unsigned*)g,
      (__attribute__((address_space(3))) unsigned*)l, 16, 0, 0);
}
// float-offset of token n's output row (also where its bf16 tok staging lives)
__device__ inline int row_base(int n) {
  int bb = n / CDIM, c = n - bb * CDIM;
  return (c < NZ) ? (int)(ZP_OFF + (long long)(bb * NZ + c) * DIN)
                  : (int)(XP_OFF + (long long)(bb * (CDIM - NZ) + (c - NZ)) * DIN);
}

// ---------------- K0: weight prep + gate + tok staging ----------------
// blocks 0-71:  ewb_t[e][h][k] = bf16(expert_w[e][k][h])
// blocks 72-83: fwb = bf16(ffn1_w)
// blocks 84+ :  gate, 16 tokens/block, 16 lanes/token (ls=l&15 owns dims
//               ls*4+64k, k=0..11).  ALL 24 x/xi float4 loads hoisted into
//               full-unroll register arrays (issued back-to-back, one
//               latency round-trip per wave instead of 12).
__global__ __launch_bounds__(256) void pre_kernel(
    const float* __restrict__ x, const float* __restrict__ xi,
    const float* __restrict__ wg, const float* __restrict__ ew,
    const float* __restrict__ fw,
    float* __restrict__ out, float4* __restrict__ rec,
    unsigned short* __restrict__ ewb_t, unsigned short* __restrict__ fwb)
{
  int b = blockIdx.x, tid = threadIdx.x;
  __shared__ __align__(16) char sbuf[21504];   // t_lds (16.6KB) or wg padded (21KB)
  if (b < 72) {
    float (*t_lds)[65] = (float(*)[65])sbuf;
    int e = b / 12, kc = (b % 12) * 64;
    const float* src = ew + (size_t)e * DIN * HID + (size_t)kc * HID;
    #pragma unroll
    for (int it = 0; it < 16; ++it) {
      int f = it * 256 + tid; int ky = f >> 6, h = f & 63;
      t_lds[h][ky] = src[ky * 64 + h];
    }
    __syncthreads();
    unsigned short* dst = ewb_t + (size_t)e * DIN * HID + kc;
    #pragma unroll
    for (int it = 0; it < 16; ++it) {
      int f = it * 256 + tid; int h = f >> 6, ky = f & 63;
      dst[(size_t)h * DIN + ky] = f2bf(t_lds[h][ky]);
    }
    return;
  }
  if (b < 84) {
    int base = (b - 72) * 4096;
    #pragma unroll
    for (int it = 0; it < 16; ++it) {
      int idx = base + it * 256 + tid;
      fwb[idx] = f2bf(fw[idx]);
    }
    return;
  }
  // ---- gate + tok ----
  // padded wg: group g (4 dims) -> 28 floats at g*28; float j = (d&3)*6+e
  float* wgl = (float*)sbuf;
  for (int i = tid; i < NEXP * DIN; i += 256) {
    int d = i / 6, e = i - d * 6;
    wgl[(d >> 2) * 28 + (d & 3) * 6 + e] = wg[i];
  }
  __syncthreads();

  int lane = tid & 63, wid = tid >> 6;
  int ls = lane & 15;                      // dim-group within token
  int n  = (b - 84) * 16 + wid * 4 + (lane >> 4);

  const float4* xv  = reinterpret_cast<const float4*>(x  + (size_t)n * DIN);
  const float4* iv  = reinterpret_cast<const float4*>(xi + (size_t)n * DIN);
  unsigned short* tk = (unsigned short*)out + (size_t)row_base(n) * 2;

  // issue ALL loads first: 24 independent 16B loads in flight per lane
  float4 va[12], qa[12];
  #pragma unroll
  for (int k = 0; k < 12; ++k) va[k] = xv[ls + 16 * k];
  #pragma unroll
  for (int k = 0; k < 12; ++k) qa[k] = iv[ls + 16 * k];

  float lg[NEXP];
  #pragma unroll
  for (int e = 0; e < NEXP; ++e) lg[e] = 0.f;

  #pragma unroll
  for (int k = 0; k < 12; ++k) {
    float tv0 = va[k].x + qa[k].x, tv1 = va[k].y + qa[k].y;
    float tv2 = va[k].z + qa[k].z, tv3 = va[k].w + qa[k].w;
    short4v t4;
    t4[0] = (short)f2bf(tv0); t4[1] = (short)f2bf(tv1);
    t4[2] = (short)f2bf(tv2); t4[3] = (short)f2bf(tv3);
    *(short4v*)(tk + ls * 4 + 64 * k) = t4;
    const float4* wq = (const float4*)(wgl + (ls + 16 * k) * 28);
    float4 w0 = wq[0], w1 = wq[1], w2 = wq[2], w3 = wq[3], w4 = wq[4], w5 = wq[5];
    lg[0] += tv0 * w0.x; lg[1] += tv0 * w0.y; lg[2] += tv0 * w0.z;
    lg[3] += tv0 * w0.w; lg[4] += tv0 * w1.x; lg[5] += tv0 * w1.y;
    lg[0] += tv1 * w1.z; lg[1] += tv1 * w1.w; lg[2] += tv1 * w2.x;
    lg[3] += tv1 * w2.y; lg[4] += tv1 * w2.z; lg[5] += tv1 * w2.w;
    lg[0] += tv2 * w3.x; lg[1] += tv2 * w3.y; lg[2] += tv2 * w3.z;
    lg[3] += tv2 * w3.w; lg[4] += tv2 * w4.x; lg[5] += tv2 * w4.y;
    lg[0] += tv3 * w4.z; lg[1] += tv3 * w4.w; lg[2] += tv3 * w5.x;
    lg[3] += tv3 * w5.y; lg[4] += tv3 * w5.z; lg[5] += tv3 * w5.w;
  }
  // reduce over the 16 lanes of this token's group
  #pragma unroll
  for (int e = 0; e < NEXP; ++e) {
    float v = lg[e];
    v += __shfl_xor(v, 1, 64);
    v += __shfl_xor(v, 2, 64);
    v += __shfl_xor(v, 4, 64);
    v += __shfl_xor(v, 8, 64);
    lg[e] = v;
  }
  // top-2 (computed uniformly by all 16 lanes of the group)
  int e0 = 0; float v0 = lg[0];
  #pragma unroll
  for (int j = 1; j < NEXP; ++j) if (lg[j] > v0) { v0 = lg[j]; e0 = j; }
  int e1 = 0; float v1 = -3.4e38f;
  #pragma unroll
  for (int j = 0; j < NEXP; ++j) if (j != e0 && lg[j] > v1) { v1 = lg[j]; e1 = j; }
  float g0 = 1.f / (1.f + expf(v1 - v0));
  if (ls < NEXP) {
    float myv = lg[0];
    #pragma unroll
    for (int e = 1; e < NEXP; ++e) if (ls == e) myv = lg[e];
    out[LG_OFF + (size_t)n * NEXP + ls] = myv;
  }
  if (ls == 0) rec[n] = make_float4((float)e0, (float)e1, g0, 1.f - g0);
}

// ---------------- K1: GEMM (all experts) + combine + FFN, counted-vmcnt ----
// M=64 tok/block, N=384, BK=32, 24 phases, 512 threads (8 waves 2x4).
// Block 320 computes the load-balance loss.  (round-4 verified, verbatim)
__global__ __launch_bounds__(512) void moe_kernel(
    const unsigned short* __restrict__ ewb_t, const float* __restrict__ eb,
    const unsigned short* __restrict__ fwb, const float* __restrict__ fb,
    const float4* __restrict__ rec, float* __restrict__ out)
{
  __shared__ __align__(16) char smem[74752];
  __shared__ int rb[64];
  __shared__ float simp[8][NEXP], sld[8][NEXP];

  int tid = threadIdx.x, lane = tid & 63, wid = tid >> 6;
  int qw = lane >> 4, l15 = lane & 15;
  int wm = wid >> 2, wn = wid & 3;

  if (blockIdx.x == 320) {   // ---- loss ----
    float imp[NEXP], ld[NEXP];
    #pragma unroll
    for (int e = 0; e < NEXP; ++e) { imp[e] = 0.f; ld[e] = 0.f; }
    for (int n = tid; n < NTOK; n += 512) {
      float4 r = rec[n];
      int e0 = (int)r.x, e1 = (int)r.y;
      #pragma unroll
      for (int e = 0; e < NEXP; ++e) {
        imp[e] += (e == e0 ? r.z : 0.f) + (e == e1 ? r.w : 0.f);
        ld[e]  += (e == e0 ? 1.f : 0.f) + (e == e1 ? 1.f : 0.f);
      }
    }
    #pragma unroll
    for (int e = 0; e < NEXP; ++e) {
      float a = imp[e], bq = ld[e];
      #pragma unroll
      for (int off = 32; off >= 1; off >>= 1) {
        a += __shfl_xor(a, off, 64);
        bq += __shfl_xor(bq, off, 64);
      }
      imp[e] = a; ld[e] = bq;
    }
    if (lane == 0) {
      #pragma unroll
      for (int e = 0; e < NEXP; ++e) { simp[wid][e] = imp[e]; sld[wid][e] = ld[e]; }
    }
    __syncthreads();
    if (tid == 0) {
      float It[NEXP], Lt[NEXP], mi = 0.f, ml = 0.f;
      #pragma unroll
      for (int e = 0; e < NEXP; ++e) {
        It[e] = 0.f; Lt[e] = 0.f;
        #pragma unroll
        for (int w = 0; w < 8; ++w) { It[e] += simp[w][e]; Lt[e] += sld[w][e]; }
        mi += It[e]; ml += Lt[e];
      }
      mi /= NEXP; ml /= NEXP;
      float vi = 0.f, vl = 0.f;
      #pragma unroll
      for (int e = 0; e < NEXP; ++e) {
        vi += (It[e] - mi) * (It[e] - mi);
        vl += (Lt[e] - ml) * (Lt[e] - ml);
      }
      vi /= NEXP; vl /= NEXP;
      out[LOSS_OFF] = vi / (mi * mi + 1e-10f) + vl / (ml * ml + 1e-10f);
    }
    return;
  }

  int t0 = blockIdx.x * 64;
  const unsigned short* tokb = (const unsigned short*)out;

  // per-thread staging sources
  size_t b_src[3]; int b_dst[3];
  #pragma unroll
  for (int it = 0; it < 3; ++it) {
    int F = it * 512 + tid, r = F >> 2, s = F & 3;
    b_src[it] = (size_t)r * DIN + ((s ^ (r & 3) ^ ((r & 4) >> 1)) << 3);
    b_dst[it] = (it * 512 + wid * 64) * 16;
  }
  int ar = tid >> 2, as = tid & 3;
  size_t a_src = (size_t)row_base(t0 + ar) * 2 +
                 ((as ^ (ar & 3) ^ ((ar & 4) >> 1)) << 3);
  int a_dst = (wid * 64) * 16;

  if (tid < 64) rb[tid] = row_base(t0 + tid);

  // prologue: chunk 0
  #pragma unroll
  for (int it = 0; it < 3; ++it)
    gload16(ewb_t + b_src[it], smem + 8192 + b_dst[it]);
  if (tid < 256) gload16(tokb + a_src, smem + a_dst);

  f32x4 acc[2][6];
  #pragma unroll
  for (int m = 0; m < 2; ++m)
    #pragma unroll
    for (int n = 0; n < 6; ++n) acc[m][n] = (f32x4){0.f, 0.f, 0.f, 0.f};

  int aoff[2], boff[6];
  #pragma unroll
  for (int m = 0; m < 2; ++m) {
    int row = wm * 32 + m * 16 + l15;
    aoff[m] = row * 64 + ((qw ^ (row & 3) ^ ((row & 4) >> 1)) << 4);
  }
  #pragma unroll
  for (int n = 0; n < 6; ++n) {
    int row = wn * 96 + n * 16 + l15;
    boff[n] = row * 64 + ((qw ^ (row & 3) ^ ((row & 4) >> 1)) << 4);
  }

  // K-loop: 24 phases, counted vmcnt, 2 raw barriers per phase
  for (int k = 0; k < 24; ++k) {
    const char* cA = smem + (k & 1) * 4096;
    const char* cB = smem + 8192 + (k & 1) * 24576;
    char* nA = (char*)smem + ((k + 1) & 1) * 4096;
    char* nB = (char*)smem + 8192 + ((k + 1) & 1) * 24576;
    if (k < 23) {
      #pragma unroll
      for (int it = 0; it < 3; ++it)
        gload16(ewb_t + b_src[it] + (k + 1) * 32, nB + b_dst[it]);
      if (tid < 256) gload16(tokb + a_src + (k + 1) * 32, nA + a_dst);
      if (wid < 4) VM(4); else VM(3);
    } else {
      VM(0);
    }
    __builtin_amdgcn_s_barrier();
    __builtin_amdgcn_sched_barrier(0);
    short8 af[2], bfv[6];
    #pragma unroll
    for (int m = 0; m < 2; ++m) af[m] = *(const short8*)(cA + aoff[m]);
    #pragma unroll
    for (int n = 0; n < 6; ++n) bfv[n] = *(const short8*)(cB + boff[n]);
    __builtin_amdgcn_s_setprio(1);
    #pragma unroll
    for (int m = 0; m < 2; ++m)
      #pragma unroll
      for (int n = 0; n < 6; ++n)
        acc[m][n] = __builtin_amdgcn_mfma_f32_16x16x32_bf16(af[m], bfv[n], acc[m][n], 0, 0, 0);
    __builtin_amdgcn_s_setprio(0);
    __builtin_amdgcn_sched_barrier(0);
    __builtin_amdgcn_s_barrier();
  }

  // issue fwb chunk 0 into HI buffer (in flight during h/combine)
  #pragma unroll
  for (int it = 0; it < 2; ++it) {
    int F = it * 512 + tid, r = F >> 3, s = F & 7;
    gload16(fwb + (size_t)r * HID + ((s ^ (r & 7)) << 3),
            smem + 58368 + (it * 512 + wid * 64) * 16);
  }

  // h -> LDS bf16 [64][392]
  unsigned short* hl = (unsigned short*)(smem + 8192);
  #pragma unroll
  for (int m = 0; m < 2; ++m)
    #pragma unroll
    for (int n = 0; n < 6; ++n)
      #pragma unroll
      for (int i = 0; i < 4; ++i) {
        int row = wm * 32 + m * 16 + qw * 4 + i;
        int col = wn * 96 + n * 16 + l15;
        hl[row * 392 + col] = f2bf(acc[m][n][i]);
      }
  LGKM0;
  __builtin_amdgcn_s_barrier();

  // gated combine -> y bf16 (swizzled) at smem[0,8192)
  {
    int t = tid >> 3, j0 = (tid & 7) * 8;
    float4 rr = rec[t0 + t];
    int e0 = (int)rr.x, e1 = (int)rr.y;
    float g0 = rr.z, g1 = rr.w;
    short8 h0 = *(const short8*)(hl + t * 392 + e0 * 64 + j0);
    short8 h1 = *(const short8*)(hl + t * 392 + e1 * 64 + j0);
    const float4* ep0 = (const float4*)(eb + e0 * 64 + j0);
    const float4* ep1 = (const float4*)(eb + e1 * 64 + j0);
    float4 b0a = ep0[0], b0b = ep0[1], b1a = ep1[0], b1b = ep1[1];
    float be0[8] = {b0a.x, b0a.y, b0a.z, b0a.w, b0b.x, b0b.y, b0b.z, b0b.w};
    float be1[8] = {b1a.x, b1a.y, b1a.z, b1a.w, b1b.x, b1b.y, b1b.z, b1b.w};
    short8 ov;
    #pragma unroll
    for (int j = 0; j < 8; ++j) {
      float v = g0 * (b2f((unsigned short)h0[j]) + be0[j])
              + g1 * (b2f((unsigned short)h1[j]) + be1[j]);
      ov[j] = (short)f2bf(v);
    }
    *(short8*)(smem + t * 128 + ((((tid & 7)) ^ (t & 7)) << 4)) = ov;
  }
  LGKM0;
  __builtin_amdgcn_s_barrier();

  // FFN: 6 chunks of 128 cols, fwb dbuf HI/LO, counted vmcnt
  for (int c = 0; c < 6; ++c) {
    const char* cF = smem + ((c & 1) ? 8192 : 58368);
    char* nF = (char*)smem + ((c & 1) ? 58368 : 8192);
    if (c < 5) {
      #pragma unroll
      for (int it = 0; it < 2; ++it) {
        int F = it * 512 + tid, r = F >> 3, s = F & 7;
        gload16(fwb + (size_t)((c + 1) * 128 + r) * HID + ((s ^ (r & 7)) << 3),
                nF + (it * 512 + wid * 64) * 16);
      }
      VM(2);
    } else {
      VM(0);
    }
    __builtin_amdgcn_s_barrier();
    __builtin_amdgcn_sched_barrier(0);
    f32x4 a2[2][2];
    #pragma unroll
    for (int m = 0; m < 2; ++m)
      #pragma unroll
      for (int n = 0; n < 2; ++n) a2[m][n] = (f32x4){0.f, 0.f, 0.f, 0.f};
    #pragma unroll
    for (int kk = 0; kk < 2; ++kk) {
      short8 ay[2], bw[2];
      #pragma unroll
      for (int m = 0; m < 2; ++m) {
        int row = wm * 32 + m * 16 + l15;
        ay[m] = *(const short8*)(smem + row * 128 + (((kk * 4 + qw) ^ (row & 7)) << 4));
      }
      #pragma unroll
      for (int n = 0; n < 2; ++n) {
        int rw = wn * 32 + n * 16 + l15;
        bw[n] = *(const short8*)(cF + rw * 128 + (((kk * 4 + qw) ^ (rw & 7)) << 4));
      }
      __builtin_amdgcn_s_setprio(1);
      #pragma unroll
      for (int m = 0; m < 2; ++m)
        #pragma unroll
        for (int n = 0; n < 2; ++n)
          a2[m][n] = __builtin_amdgcn_mfma_f32_16x16x32_bf16(ay[m], bw[n], a2[m][n], 0, 0, 0);
      __builtin_amdgcn_s_setprio(0);
    }
    #pragma unroll
    for (int n = 0; n < 2; ++n) {
      int col = c * 128 + wn * 32 + n * 16 + l15;
      float bias = fb[col];
      #pragma unroll
      for (int m = 0; m < 2; ++m)
        #pragma unroll
        for (int i = 0; i < 4; ++i) {
          int rl = wm * 32 + m * 16 + qw * 4 + i;
          out[(size_t)rb[rl] + col] = a2[m][n][i] + bias;
        }
    }
    __builtin_amdgcn_sched_barrier(0);
    __builtin_amdgcn_s_barrier();
  }
}

}  // namespace

extern "C" void kernel_launch(void* const* d_in, const int* in_sizes, int n_in,
                              void* d_out, int out_size, void* d_ws, size_t ws_size,
                              hipStream_t stream)
{
  const float* x  = (const float*)d_in[0];
  const float* xi = (const float*)d_in[1];
  const float* wg = (const float*)d_in[2];
  const float* ew = (const float*)d_in[3];
  const float* eb = (const float*)d_in[4];
  const float* fw = (const float*)d_in[5];
  const float* fb = (const float*)d_in[6];
  float* out = (float*)d_out;

  char* w = (char*)d_ws;
  float4*         rec   = (float4*)w;                              // 327,680 B
  unsigned short* ewb_t = (unsigned short*)(w + 327680);           // 589,824 B
  unsigned short* fwb   = (unsigned short*)(w + 327680 + 589824);  //  98,304 B

  // gate: 1280 blocks x 16 tokens, loads register-hoisted; +84 prep blocks
  pre_kernel<<<84 + 1280, 256, 0, stream>>>(x, xi, wg, ew, fw, out, rec, ewb_t, fwb);
  moe_kernel<<<321, 512, 0, stream>>>(ewb_t, eb, fwb, fb, rec, out);
}